// Round 2
// baseline (179.384 us; speedup 1.0000x reference)
//
#include <hip/hip_runtime.h>
#include <hip/hip_bf16.h>

#define NB 8        // batches
#define SS 4096
#define DD 1024
#define NI 4094     // score entries per batch
#define MT 33       // m-tiles per batch, stride 126 (2-row overlap)
#define MSTRIDE 126
#define BK 64

typedef __attribute__((ext_vector_type(8))) short short8;
typedef __attribute__((ext_vector_type(4))) float f32x4;

// ---- ws layout (bytes) ----
// [0, 2 MB)   : Wb bf16 [1024][1024]
// [2 MB, 3 MB): pn f32 [8][4096][8]   (n_i = ||C[i+1]-C[i]||^2 partials, i<4095)
// [3 MB, 4 MB): pc f32 [8][4096][8]   (c_i partials, i<4094)
#define WB_OFF 0
#define PN_OFF (2*1024*1024)
#define PC_OFF (PN_OFF + NB*SS*8*4)

__device__ __forceinline__ unsigned short f2bf(float f) {
    union { float f; unsigned int u; } v; v.f = f;
    unsigned int r = v.u + 0x7FFFu + ((v.u >> 16) & 1u);   // RNE
    return (unsigned short)(r >> 16);
}
__device__ __forceinline__ float bf2f(unsigned short u) {
    union { unsigned int u; float f; } v; v.u = ((unsigned int)u) << 16;
    return v.f;
}

__device__ __forceinline__ void gload_lds16(const void* g, void* l) {
    __builtin_amdgcn_global_load_lds(
        (const __attribute__((address_space(1))) void*)g,
        (__attribute__((address_space(3))) void*)l, 16, 0, 0);
}

// ---- pass 0: W -> bf16 ----
__global__ void conv_w(const float* __restrict__ W, unsigned short* __restrict__ Wb) {
    int i = (blockIdx.x * 256 + threadIdx.x) * 4;
    float4 a = *(const float4*)(W + i);
    ushort4 o;
    o.x = f2bf(a.x); o.y = f2bf(a.y); o.z = f2bf(a.z); o.w = f2bf(a.w);
    *(ushort4*)(Wb + i) = o;
}

// ---- pass 1: GEMM C = x @ W^T (bf16 MFMA), fused adjacent-row-diff epilogue ----
// grid: (8 n-tiles, 33 m-tiles, 8 batches), block 256 (4 waves, 2x2)
// A (x-tile) reg-staged: f32 load -> cvt_pk bf16 -> XOR-swizzled ds_write
// B (W-tile) via global_load_lds(16B): linear LDS dest + inverse-swizzled source
__launch_bounds__(256, 4)
__global__ void gemm_nc(const float* __restrict__ x,
                        const unsigned short* __restrict__ Wb,
                        float* __restrict__ pn, float* __restrict__ pc) {
    __shared__ __align__(16) char smem[34816];
    char* Alds = smem;              // 16 KB, swizzled [128][64] bf16
    char* Blds = smem + 16384;      // 16 KB, swizzled [128][64] bf16

    const int t = threadIdx.x;
    const int bn = blockIdx.x;      // 0..7  (N-tile)
    const int mt = blockIdx.y;      // 0..32 (M-tile)
    const int b  = blockIdx.z;
    const int m0 = mt * MSTRIDE;
    const int lane = t & 63, w = t >> 6;
    const int wr = w >> 1, wc = w & 1;
    const int lrow = lane & 15, lgrp = lane >> 4;

    // A staging map: 4 passes, row = p*32 + (t>>3), 8 threads/row x 8 f32 cols
    const int arow_l = t >> 3;      // 0..31
    const int acg = t & 7;          // col-group (8 f32 = one 16B bf16 slot)
    // B gload_lds map: iter i covers rows (w*4+i)*8 .. +7, lane>>3 = row-in-8, lane&7 = slot
    const int brow_b = w * 32 + (lane >> 3);
    const int bq = lane & 7;

    const float* xb = x + (size_t)b * SS * DD;

    f32x4 acc[4][4] = {};

    for (int kt = 0; kt < 16; ++kt) {
        const int k0 = kt * BK;
        __syncthreads();
        // B: async direct-to-LDS, source pre-swizzled so linear dest + XOR read match
        #pragma unroll
        for (int i = 0; i < 4; ++i) {
            int row = brow_b + i * 8;
            const unsigned short* src =
                Wb + ((size_t)(bn * 128 + row)) * DD + k0 + ((bq ^ (row & 7)) << 3);
            gload_lds16(src, Blds + (w * 4 + i) * 1024);
        }
        // A: f32 x -> bf16, swizzled ds_write (rows >= 4096 zero-padded)
        #pragma unroll
        for (int p = 0; p < 4; ++p) {
            int row = p * 32 + arow_l;
            int grow = m0 + row;
            uint4 pkt = make_uint4(0, 0, 0, 0);
            if (grow < SS) {
                const float* xs = xb + (size_t)grow * DD + k0 + acg * 8;
                float4 a0 = *(const float4*)xs;
                float4 a1 = *(const float4*)(xs + 4);
                union { uint4 u; __hip_bfloat162 h[4]; } pk;
                pk.h[0] = __float22bfloat162_rn(make_float2(a0.x, a0.y));
                pk.h[1] = __float22bfloat162_rn(make_float2(a0.z, a0.w));
                pk.h[2] = __float22bfloat162_rn(make_float2(a1.x, a1.y));
                pk.h[3] = __float22bfloat162_rn(make_float2(a1.z, a1.w));
                pkt = pk.u;
            }
            *(uint4*)(Alds + row * 128 + ((acg ^ (row & 7)) << 4)) = pkt;
        }
        __syncthreads();   // drains vmcnt (gload_lds) + lgkmcnt (ds_write)
        #pragma unroll
        for (int kk = 0; kk < 2; ++kk) {
            short8 af[4], bfr[4];
            #pragma unroll
            for (int m = 0; m < 4; ++m) {
                int row = wr * 64 + m * 16 + lrow;
                int s = (kk * 4 + lgrp) ^ (row & 7);
                af[m] = *(const short8*)(Alds + row * 128 + s * 16);
            }
            #pragma unroll
            for (int n = 0; n < 4; ++n) {
                int row = wc * 64 + n * 16 + lrow;
                int s = (kk * 4 + lgrp) ^ (row & 7);
                bfr[n] = *(const short8*)(Blds + row * 128 + s * 16);
            }
            #pragma unroll
            for (int m = 0; m < 4; ++m)
                #pragma unroll
                for (int n = 0; n < 4; ++n)
                    acc[m][n] = __builtin_amdgcn_mfma_f32_16x16x32_bf16(
                        af[m], bfr[n], acc[m][n], 0, 0, 0);
        }
    }

    // epilogue: C tile -> LDS bf16 [128][136]
    __syncthreads();
    unsigned short* Ylds = (unsigned short*)smem;
    #pragma unroll
    for (int m = 0; m < 4; ++m) {
        int rbase = wr * 64 + m * 16 + lgrp * 4;   // C/D: row=(lane>>4)*4+reg
        #pragma unroll
        for (int n = 0; n < 4; ++n) {
            int col = wc * 64 + n * 16 + lrow;     // C/D: col=lane&15
            #pragma unroll
            for (int j = 0; j < 4; ++j)
                Ylds[(rbase + j) * 136 + col] = f2bf(acc[m][n][j]);
        }
    }
    __syncthreads();

    // adjacent-row differences: thread -> (row r = t>>1, half h = t&1), 64 cols
    int r = t >> 1, h = t & 1;
    float sn = 0.f, sc = 0.f;
    if (r < 127) {
        const unsigned short* y0 = Ylds + r * 136 + h * 64;
        const unsigned short* y1 = y0 + 136;
        bool hv2 = (r < 126);
        #pragma unroll
        for (int c8 = 0; c8 < 8; ++c8) {
            short8 v0 = *(const short8*)(y0 + c8 * 8);
            short8 v1 = *(const short8*)(y1 + c8 * 8);
            short8 v2 = v1;
            if (hv2) v2 = *(const short8*)(y1 + 136 + c8 * 8);
            #pragma unroll
            for (int j = 0; j < 8; ++j) {
                float f0 = bf2f((unsigned short)v0[j]);
                float f1 = bf2f((unsigned short)v1[j]);
                float f2 = bf2f((unsigned short)v2[j]);
                float d0 = f1 - f0;
                float d1 = f2 - f1;
                sn += d0 * d0;
                sc += d0 * d1;
            }
        }
    }
    sn += __shfl_xor(sn, 1);
    sc += __shfl_xor(sc, 1);
    if (h == 0 && r < 127) {
        int i = m0 + r;
        if (i < SS - 1)
            pn[((size_t)b * SS + i) * 8 + bn] = sn;    // i in [0,4095)
        if (r < 126 && i < NI)
            pc[((size_t)b * SS + i) * 8 + bn] = sc;    // i in [0,4094)
    }
}

// ---- pass 2: combine partials -> scores -> adj ----
__global__ void score_k(const float* __restrict__ pn, const float* __restrict__ pc,
                        const float* __restrict__ gate, float* __restrict__ out) {
    int tid = blockIdx.x * 256 + threadIdx.x;
    const int total = NB * NI;
    if (tid >= total) return;
    int b = tid / NI;
    int i = tid - b * NI;
    size_t base = ((size_t)b * SS + i) * 8;
    float n0 = 0.f, n1 = 0.f, c0 = 0.f;
    #pragma unroll
    for (int j = 0; j < 8; ++j) {
        n0 += pn[base + j];
        n1 += pn[base + 8 + j];
        c0 += pc[base + j];
    }
    float d1a = sqrtf(fmaxf(n0, 0.f));
    float d1b = sqrtf(fmaxf(n1, 0.f));
    float d2  = sqrtf(fmaxf(n0 + 2.f * c0 + n1, 0.f));
    float path = d1a + d1b;
    float s = 1.f - (path - d2) / fmaxf(d2, 1e-6f);
    s = fmaxf(s, 0.f);
    float g = gate[0] * 0.5f;
    float adj = g * (s * (1.f / (float)NI) - 0.5f) * 0.1f;
    out[(size_t)b * SS + i + 1] = adj;
    if (i == 0) {
        float e = g * (-0.5f) * 0.1f;
        out[(size_t)b * SS] = e;
        out[(size_t)b * SS + SS - 1] = e;
    }
}

extern "C" void kernel_launch(void* const* d_in, const int* in_sizes, int n_in,
                              void* d_out, int out_size, void* d_ws, size_t ws_size,
                              hipStream_t stream) {
    const float* x    = (const float*)d_in[0];
    const float* W    = (const float*)d_in[1];
    // d_in[2] (bias) cancels in all distances -> unused
    const float* gate = (const float*)d_in[3];
    float* out = (float*)d_out;
    char* ws = (char*)d_ws;

    unsigned short* Wb = (unsigned short*)(ws + WB_OFF);
    float* pn = (float*)(ws + PN_OFF);
    float* pc = (float*)(ws + PC_OFF);

    conv_w<<<1024, 256, 0, stream>>>(W, Wb);
    dim3 g(8, MT, NB);
    gemm_nc<<<g, 256, 0, stream>>>(x, Wb, pn, pc);
    score_k<<<(NB * NI + 255) / 256, 256, 0, stream>>>(pn, pc, gate, out);
}

// Round 3
// 135.376 us; speedup vs baseline: 1.3251x; 1.3251x over previous
//
#include <hip/hip_runtime.h>
#include <hip/hip_bf16.h>

#define NB 8        // batches
#define SS 4096
#define DD 1024
#define NI 4094     // score entries per batch
#define MT 33       // m-tiles per batch, stride 126 (2-row overlap)
#define MSTRIDE 126
#define RPAD 4224   // padded rows per batch (33*126 + 2 tail, zeroed)
#define BK 64

typedef __attribute__((ext_vector_type(8))) short short8;
typedef __attribute__((ext_vector_type(4))) float f32x4;

// ---- ws layout (bytes) ----
// [0, 2 MB)        : Wb bf16 [1024][1024]
// [2 MB, +66 MB)   : xb bf16 [8][4224][1024]  (rows >=4096 zeroed)
// then pn f32 [8][4096][8], pc f32 [8][4096][8]
#define WB_OFF 0
#define XB_OFF (2*1024*1024)
#define PN_OFF (XB_OFF + NB*RPAD*DD*2)
#define PC_OFF (PN_OFF + NB*SS*8*4)

__device__ __forceinline__ unsigned short f2bf(float f) {
    union { float f; unsigned int u; } v; v.f = f;
    unsigned int r = v.u + 0x7FFFu + ((v.u >> 16) & 1u);   // RNE
    return (unsigned short)(r >> 16);
}
__device__ __forceinline__ float bf2f(unsigned short u) {
    union { unsigned int u; float f; } v; v.u = ((unsigned int)u) << 16;
    return v.f;
}

__device__ __forceinline__ void gload_lds16(const void* g, void* l) {
    __builtin_amdgcn_global_load_lds(
        (const __attribute__((address_space(1))) void*)g,
        (__attribute__((address_space(3))) void*)l, 16, 0, 0);
}

// ---- pass 0a: W -> bf16 ----
__global__ void conv_w(const float* __restrict__ W, unsigned short* __restrict__ Wb) {
    int i = (blockIdx.x * 256 + threadIdx.x) * 4;
    float4 a = *(const float4*)(W + i);
    ushort4 o;
    o.x = f2bf(a.x); o.y = f2bf(a.y); o.z = f2bf(a.z); o.w = f2bf(a.w);
    *(ushort4*)(Wb + i) = o;
}

// ---- pass 0b: x -> bf16 (single read of x), zero-pad rows 4096..4223 ----
__global__ void conv_xb(const float* __restrict__ x, unsigned short* __restrict__ xb) {
    int tid = blockIdx.x * 256 + threadIdx.x;     // NB*RPAD*128 threads, 8 elems each
    int b   = tid / (RPAD * 128);
    int rem = tid - b * (RPAD * 128);
    int row = rem >> 7;
    int c0  = (rem & 127) * 8;
    ushort4 o0 = make_ushort4(0, 0, 0, 0), o1 = o0;
    if (row < SS) {
        const float* p = x + ((size_t)b * SS + row) * DD + c0;
        float4 a0 = *(const float4*)p;
        float4 a1 = *(const float4*)(p + 4);
        o0.x = f2bf(a0.x); o0.y = f2bf(a0.y); o0.z = f2bf(a0.z); o0.w = f2bf(a0.w);
        o1.x = f2bf(a1.x); o1.y = f2bf(a1.y); o1.z = f2bf(a1.z); o1.w = f2bf(a1.w);
    }
    unsigned short* q = xb + ((size_t)b * RPAD + row) * DD + c0;
    *(ushort4*)q = o0;
    *(ushort4*)(q + 4) = o1;
}

// ---- pass 1: GEMM C = xb @ Wb^T (bf16 MFMA), double-buffered 2-phase,
//      both operands via global_load_lds(16B) + pre-swizzled source,
//      fused adjacent-row-diff epilogue.
// grid: (8 n-tiles, 33 m-tiles, 8 batches), block 256 (4 waves, 2x2)
__launch_bounds__(256, 2)
__global__ void gemm_nc(const unsigned short* __restrict__ xb,
                        const unsigned short* __restrict__ Wb,
                        float* __restrict__ pn, float* __restrict__ pc) {
    __shared__ __align__(16) char smem[65536];
    // A0 @0, B0 @16384, A1 @32768, B1 @49152 — each swizzled [128][64] bf16

    const int t = threadIdx.x;
    const int bn = blockIdx.x;      // 0..7  (N-tile)
    const int mt = blockIdx.y;      // 0..32 (M-tile)
    const int b  = blockIdx.z;
    const int m0 = mt * MSTRIDE;
    const int lane = t & 63, w = t >> 6;
    const int wr = w >> 1, wc = w & 1;
    const int lrow = lane & 15, lgrp = lane >> 4;
    // staging map: wave w iter i covers rows w*32+i*8 .. +7; lane>>3 = row-in-8, lane&7 = 16B slot
    const int srow = w * 32 + (lane >> 3);
    const int sq = lane & 7;

    const unsigned short* Abase = xb + ((size_t)b * RPAD + m0) * DD;
    const unsigned short* Bbase = Wb + (size_t)bn * 128 * DD;

    f32x4 acc[4][4] = {};

    auto stage = [&](int k0, char* Al, char* Bl) {
        #pragma unroll
        for (int i = 0; i < 4; ++i) {
            int row = srow + i * 8;
            size_t goff = (size_t)row * DD + k0 + ((sq ^ (row & 7)) << 3);
            gload_lds16(Abase + goff, Al + (w * 4 + i) * 1024);
            gload_lds16(Bbase + goff, Bl + (w * 4 + i) * 1024);
        }
    };
    auto compute = [&](const char* Al, const char* Bl) {
        #pragma unroll
        for (int kk = 0; kk < 2; ++kk) {
            short8 af[4], bfr[4];
            #pragma unroll
            for (int m = 0; m < 4; ++m) {
                int row = wr * 64 + m * 16 + lrow;
                int s = (kk * 4 + lgrp) ^ (row & 7);
                af[m] = *(const short8*)(Al + row * 128 + s * 16);
            }
            #pragma unroll
            for (int n = 0; n < 4; ++n) {
                int row = wc * 64 + n * 16 + lrow;
                int s = (kk * 4 + lgrp) ^ (row & 7);
                bfr[n] = *(const short8*)(Bl + row * 128 + s * 16);
            }
            #pragma unroll
            for (int m = 0; m < 4; ++m)
                #pragma unroll
                for (int n = 0; n < 4; ++n)
                    acc[m][n] = __builtin_amdgcn_mfma_f32_16x16x32_bf16(
                        af[m], bfr[n], acc[m][n], 0, 0, 0);
        }
    };

    char* Acur = smem;            char* Bcur = smem + 16384;
    char* Anxt = smem + 32768;    char* Bnxt = smem + 49152;

    stage(0, Acur, Bcur);
    __syncthreads();
    for (int kt = 0; kt < 16; ++kt) {
        if (kt < 15) stage((kt + 1) * BK, Anxt, Bnxt);  // issue next-tile loads FIRST
        compute(Acur, Bcur);                            // ds_read + MFMA on current
        __syncthreads();                                // one drain+barrier per K-step
        char* tA = Acur; Acur = Anxt; Anxt = tA;
        char* tB = Bcur; Bcur = Bnxt; Bnxt = tB;
    }

    // epilogue: C tile -> LDS bf16 [128][136] (reuses smem; loop's last sync covers)
    unsigned short* Ylds = (unsigned short*)smem;
    #pragma unroll
    for (int m = 0; m < 4; ++m) {
        int rbase = wr * 64 + m * 16 + lgrp * 4;   // C/D: row=(lane>>4)*4+reg
        #pragma unroll
        for (int n = 0; n < 4; ++n) {
            int col = wc * 64 + n * 16 + lrow;     // C/D: col=lane&15
            #pragma unroll
            for (int j = 0; j < 4; ++j)
                Ylds[(rbase + j) * 136 + col] = f2bf(acc[m][n][j]);
        }
    }
    __syncthreads();

    // adjacent-row differences: thread -> (row r = t>>1, half h = t&1), 64 cols
    int r = t >> 1, h = t & 1;
    float sn = 0.f, sc = 0.f;
    if (r < 127) {
        const unsigned short* y0 = Ylds + r * 136 + h * 64;
        const unsigned short* y1 = y0 + 136;
        bool hv2 = (r < 126);
        #pragma unroll
        for (int c8 = 0; c8 < 8; ++c8) {
            short8 v0 = *(const short8*)(y0 + c8 * 8);
            short8 v1 = *(const short8*)(y1 + c8 * 8);
            short8 v2 = v1;
            if (hv2) v2 = *(const short8*)(y1 + 136 + c8 * 8);
            #pragma unroll
            for (int j = 0; j < 8; ++j) {
                float f0 = bf2f((unsigned short)v0[j]);
                float f1 = bf2f((unsigned short)v1[j]);
                float f2 = bf2f((unsigned short)v2[j]);
                float d0 = f1 - f0;
                float d1 = f2 - f1;
                sn += d0 * d0;
                sc += d0 * d1;
            }
        }
    }
    sn += __shfl_xor(sn, 1);
    sc += __shfl_xor(sc, 1);
    if (h == 0 && r < 127) {
        int i = m0 + r;
        if (i < SS - 1)
            pn[((size_t)b * SS + i) * 8 + bn] = sn;    // i in [0,4095)
        if (r < 126 && i < NI)
            pc[((size_t)b * SS + i) * 8 + bn] = sc;    // i in [0,4094)
    }
}

// ---- pass 2: combine partials -> scores -> adj ----
__global__ void score_k(const float* __restrict__ pn, const float* __restrict__ pc,
                        const float* __restrict__ gate, float* __restrict__ out) {
    int tid = blockIdx.x * 256 + threadIdx.x;
    const int total = NB * NI;
    if (tid >= total) return;
    int b = tid / NI;
    int i = tid - b * NI;
    size_t base = ((size_t)b * SS + i) * 8;
    float n0 = 0.f, n1 = 0.f, c0 = 0.f;
    #pragma unroll
    for (int j = 0; j < 8; ++j) {
        n0 += pn[base + j];
        n1 += pn[base + 8 + j];
        c0 += pc[base + j];
    }
    float d1a = sqrtf(fmaxf(n0, 0.f));
    float d1b = sqrtf(fmaxf(n1, 0.f));
    float d2  = sqrtf(fmaxf(n0 + 2.f * c0 + n1, 0.f));
    float path = d1a + d1b;
    float s = 1.f - (path - d2) / fmaxf(d2, 1e-6f);
    s = fmaxf(s, 0.f);
    float g = gate[0] * 0.5f;
    float adj = g * (s * (1.f / (float)NI) - 0.5f) * 0.1f;
    out[(size_t)b * SS + i + 1] = adj;
    if (i == 0) {
        float e = g * (-0.5f) * 0.1f;
        out[(size_t)b * SS] = e;
        out[(size_t)b * SS + SS - 1] = e;
    }
}

extern "C" void kernel_launch(void* const* d_in, const int* in_sizes, int n_in,
                              void* d_out, int out_size, void* d_ws, size_t ws_size,
                              hipStream_t stream) {
    const float* x    = (const float*)d_in[0];
    const float* W    = (const float*)d_in[1];
    // d_in[2] (bias) cancels in all distances -> unused
    const float* gate = (const float*)d_in[3];
    float* out = (float*)d_out;
    char* ws = (char*)d_ws;

    unsigned short* Wb = (unsigned short*)(ws + WB_OFF);
    unsigned short* xb = (unsigned short*)(ws + XB_OFF);
    float* pn = (float*)(ws + PN_OFF);
    float* pc = (float*)(ws + PC_OFF);

    conv_w<<<1024, 256, 0, stream>>>(W, Wb);
    conv_xb<<<NB * RPAD * 128 / 256, 256, 0, stream>>>(x, xb);
    dim3 g(8, MT, NB);
    gemm_nc<<<g, 256, 0, stream>>>(xb, Wb, pn, pc);
    score_k<<<(NB * NI + 255) / 256, 256, 0, stream>>>(pn, pc, gate, out);
}

// Round 4
// 110.053 us; speedup vs baseline: 1.6300x; 1.2301x over previous
//
#include <hip/hip_runtime.h>
#include <hip/hip_bf16.h>

#define NB 8
#define SS 4096
#define DD 1024
#define NI 4094
#define NMT 16      // 256-row m-tiles per batch, non-overlapping
#define NT 32       // K-tiles (BK=32)
#define BK 32

typedef __attribute__((ext_vector_type(8))) short short8;
typedef __attribute__((ext_vector_type(4))) float f32x4;

// ---- ws layout (bytes) ----
#define WB_OFF 0                           // Wb bf16 [1024][1024]        (2 MB)
#define XB_OFF (2*1024*1024)               // xb bf16 [8][4096][1024]     (64 MB)
#define YB_OFF (XB_OFF + NB*SS*DD*2)       // ybnd bf16 [8][16][4][1024]  (1 MB)
#define PN_OFF (YB_OFF + NB*16*4*1024*2)   // pn f32 [8][4096][4]         (512 KB)
#define PC_OFF (PN_OFF + NB*SS*4*4)        // pc f32 [8][4096][4]         (512 KB)

__device__ __forceinline__ unsigned short f2bf(float f) {
    union { float f; unsigned int u; } v; v.f = f;
    unsigned int r = v.u + 0x7FFFu + ((v.u >> 16) & 1u);   // RNE
    return (unsigned short)(r >> 16);
}
__device__ __forceinline__ float bf2f(unsigned short u) {
    union { unsigned int u; float f; } v; v.u = ((unsigned int)u) << 16;
    return v.f;
}
__device__ __forceinline__ void gload_lds16(const void* g, void* l) {
    __builtin_amdgcn_global_load_lds(
        (const __attribute__((address_space(1))) void*)g,
        (__attribute__((address_space(3))) void*)l, 16, 0, 0);
}

// ---- pass 0a: W -> bf16 ----
__global__ void conv_w(const float* __restrict__ W, unsigned short* __restrict__ Wb) {
    int i = (blockIdx.x * 256 + threadIdx.x) * 4;
    float4 a = *(const float4*)(W + i);
    ushort4 o;
    o.x = f2bf(a.x); o.y = f2bf(a.y); o.z = f2bf(a.z); o.w = f2bf(a.w);
    *(ushort4*)(Wb + i) = o;
}

// ---- pass 0b: x -> bf16 (single pass, no padding needed) ----
__global__ void conv_xb(const float* __restrict__ x, unsigned short* __restrict__ xb) {
    size_t i = ((size_t)blockIdx.x * 256 + threadIdx.x) * 8;
    float4 a0 = *(const float4*)(x + i);
    float4 a1 = *(const float4*)(x + i + 4);
    ushort4 o0, o1;
    o0.x = f2bf(a0.x); o0.y = f2bf(a0.y); o0.z = f2bf(a0.z); o0.w = f2bf(a0.w);
    o1.x = f2bf(a1.x); o1.y = f2bf(a1.y); o1.z = f2bf(a1.z); o1.w = f2bf(a1.w);
    *(ushort4*)(xb + i) = o0;
    *(ushort4*)(xb + i + 4) = o1;
}

// ---- pass 1: GEMM C = xb @ Wb^T, 256x256 tile, BK=32, 8 waves,
//      3-buffer LDS pipeline, stage-2-ahead, counted vmcnt, raw s_barrier.
//      Fused adjacent-row-diff epilogue + boundary-row dump.
__launch_bounds__(512, 2)
__global__ void gemm_nc(const unsigned short* __restrict__ xb,
                        const unsigned short* __restrict__ Wb,
                        float* __restrict__ pn, float* __restrict__ pc,
                        unsigned short* __restrict__ ybnd) {
    __shared__ __align__(16) char smem[98304];   // 3 x (A 16K + B 16K)

    const int bid = blockIdx.x;
    const int vb  = (bid & 7) * 64 + (bid >> 3);   // XCD-chunk swizzle (512 = 8*64)
    const int mg  = vb >> 2, bn = vb & 3;          // m-group, n-tile
    const int b   = mg >> 4, mt = mg & 15;
    const int m0  = mt * 256;

    const int t = threadIdx.x;
    const int lane = t & 63, w = t >> 6;           // 8 waves
    const int wr = w >> 2, wc = w & 3;             // 2 x 4 wave grid
    const int lrow = lane & 15, lgrp = lane >> 4;

    const unsigned short* Abase = xb + ((size_t)b * SS + m0) * DD;
    const unsigned short* Bbase = Wb + (size_t)bn * 256 * DD;

    // staging geometry: per wave, 4 gload_lds(16B); lane l covers
    // LDS bytes base + w*1024 + l*16  <->  global row w*16 + l/4 (+128), col (l&3)*8
    const int sr0 = w * 16 + (lane >> 2);
    const int sc0 = (lane & 3) * 8;

    f32x4 acc[8][4] = {};

    char* p0 = smem;
    char* p1 = smem + 32768;
    char* p2 = smem + 65536;

    auto stage = [&](int kt, char* buf) {
        const int k0 = kt * BK;
        gload_lds16(Abase + (size_t)sr0 * DD + k0 + sc0,         buf + w * 1024);
        gload_lds16(Abase + (size_t)(sr0 + 128) * DD + k0 + sc0, buf + 8192 + w * 1024);
        gload_lds16(Bbase + (size_t)sr0 * DD + k0 + sc0,         buf + 16384 + w * 1024);
        gload_lds16(Bbase + (size_t)(sr0 + 128) * DD + k0 + sc0, buf + 16384 + 8192 + w * 1024);
    };

    stage(0, p0);
    stage(1, p1);
    asm volatile("s_waitcnt vmcnt(4)" ::: "memory");
    __builtin_amdgcn_s_barrier();
    asm volatile("" ::: "memory");

    for (int kt = 0; kt < NT; ++kt) {
        const char* A = p0;
        const char* B = p0 + 16384;
        short8 af[8], bfv[4];
        #pragma unroll
        for (int m = 0; m < 8; ++m)
            af[m] = *(const short8*)(A + (wr * 128 + m * 16 + lrow) * 64 + lgrp * 16);
        #pragma unroll
        for (int n = 0; n < 4; ++n)
            bfv[n] = *(const short8*)(B + (wc * 64 + n * 16 + lrow) * 64 + lgrp * 16);

        if (kt < NT - 2) {
            stage(kt + 2, p2);
            asm volatile("s_waitcnt vmcnt(4)" ::: "memory");  // stage(kt+1) landed (own)
        } else {
            asm volatile("s_waitcnt vmcnt(0)" ::: "memory");  // tail drain
        }
        __builtin_amdgcn_s_barrier();                          // all waves landed
        asm volatile("" ::: "memory");
        __builtin_amdgcn_sched_barrier(0);

        __builtin_amdgcn_s_setprio(1);
        #pragma unroll
        for (int m = 0; m < 8; ++m)
            #pragma unroll
            for (int n = 0; n < 4; ++n)
                acc[m][n] = __builtin_amdgcn_mfma_f32_16x16x32_bf16(
                    af[m], bfv[n], acc[m][n], 0, 0, 0);
        __builtin_amdgcn_s_setprio(0);

        char* tmp = p0; p0 = p1; p1 = p2; p2 = tmp;            // rotate buffers
    }

    // ---------------- epilogue ----------------
    __syncthreads();
    unsigned short* Y = (unsigned short*)smem;
    const int YP = 264;   // padded cols (stride 528 B, odd 16B-slot count)

    // chunk A: C rows 0..129
    if (wr == 0) {
        #pragma unroll
        for (int m = 0; m < 8; ++m) {
            int rbase = m * 16 + lgrp * 4;
            #pragma unroll
            for (int n = 0; n < 4; ++n) {
                int col = wc * 64 + n * 16 + lrow;
                #pragma unroll
                for (int j = 0; j < 4; ++j)
                    Y[(rbase + j) * YP + col] = f2bf(acc[m][n][j]);
            }
        }
    } else if (lgrp == 0) {   // rows 128,129 from wr=1, m=0, j=0,1
        #pragma unroll
        for (int n = 0; n < 4; ++n) {
            int col = wc * 64 + n * 16 + lrow;
            #pragma unroll
            for (int j = 0; j < 2; ++j)
                Y[(128 + j) * YP + col] = f2bf(acc[0][n][j]);
        }
    }
    __syncthreads();

    // dump C rows 0,1 (slots 0,1)
    if (t < 256) {
        int rr = t >> 7, cc = (t & 127) * 2;
        ushort2 v;
        v.x = Y[rr * YP + cc]; v.y = Y[rr * YP + cc + 1];
        *(ushort2*)(ybnd + ((size_t)((b * 16 + mt) * 4 + rr)) * 1024 + bn * 256 + cc) = v;
    }
    // reduce rows 0..127 (i = m0+r; rows r,r+1,r+2 all within chunk)
    {
        int r = t >> 2, q = t & 3;
        const unsigned short* y0 = Y + r * YP + q * 64;
        float sn = 0.f, sc = 0.f;
        #pragma unroll
        for (int c8 = 0; c8 < 8; ++c8) {
            short8 v0 = *(const short8*)(y0 + c8 * 8);
            short8 v1 = *(const short8*)(y0 + YP + c8 * 8);
            short8 v2 = *(const short8*)(y0 + 2 * YP + c8 * 8);
            #pragma unroll
            for (int j = 0; j < 8; ++j) {
                float f0 = bf2f((unsigned short)v0[j]);
                float f1 = bf2f((unsigned short)v1[j]);
                float f2 = bf2f((unsigned short)v2[j]);
                float d0 = f1 - f0, d1 = f2 - f1;
                sn += d0 * d0; sc += d0 * d1;
            }
        }
        sn += __shfl_xor(sn, 1); sn += __shfl_xor(sn, 2);
        sc += __shfl_xor(sc, 1); sc += __shfl_xor(sc, 2);
        if (q == 0) {
            size_t o = ((size_t)b * SS + m0 + r) * 4 + bn;
            pn[o] = sn; pc[o] = sc;
        }
    }
    __syncthreads();

    // chunk B: C rows 128..255 -> LDS rows 0..127
    if (wr == 1) {
        #pragma unroll
        for (int m = 0; m < 8; ++m) {
            int rbase = m * 16 + lgrp * 4;
            #pragma unroll
            for (int n = 0; n < 4; ++n) {
                int col = wc * 64 + n * 16 + lrow;
                #pragma unroll
                for (int j = 0; j < 4; ++j)
                    Y[(rbase + j) * YP + col] = f2bf(acc[m][n][j]);
            }
        }
    }
    __syncthreads();

    // dump C rows 254,255 (LDS rows 126,127 -> slots 2,3)
    if (t < 256) {
        int rr = t >> 7, cc = (t & 127) * 2;
        ushort2 v;
        v.x = Y[(126 + rr) * YP + cc]; v.y = Y[(126 + rr) * YP + cc + 1];
        *(ushort2*)(ybnd + ((size_t)((b * 16 + mt) * 4 + 2 + rr)) * 1024 + bn * 256 + cc) = v;
    }
    // reduce rows 128..254 (r2 = 0..126; c only to r2=125; rest via boundary kernel)
    {
        int r2 = t >> 2, q = t & 3;
        float sn = 0.f, sc = 0.f;
        if (r2 <= 126) {
            const unsigned short* y0 = Y + r2 * YP + q * 64;
            int rc = (r2 < 126) ? 2 : 1;   // clamp third row (unused when clamped)
            #pragma unroll
            for (int c8 = 0; c8 < 8; ++c8) {
                short8 v0 = *(const short8*)(y0 + c8 * 8);
                short8 v1 = *(const short8*)(y0 + YP + c8 * 8);
                short8 v2 = *(const short8*)(y0 + rc * YP + c8 * 8);
                #pragma unroll
                for (int j = 0; j < 8; ++j) {
                    float f0 = bf2f((unsigned short)v0[j]);
                    float f1 = bf2f((unsigned short)v1[j]);
                    float f2 = bf2f((unsigned short)v2[j]);
                    float d0 = f1 - f0, d1 = f2 - f1;
                    sn += d0 * d0; sc += d0 * d1;
                }
            }
        }
        sn += __shfl_xor(sn, 1); sn += __shfl_xor(sn, 2);
        sc += __shfl_xor(sc, 1); sc += __shfl_xor(sc, 2);
        if (q == 0 && r2 <= 126) {
            size_t o = ((size_t)b * SS + m0 + 128 + r2) * 4 + bn;
            pn[o] = sn;
            if (r2 <= 125) pc[o] = sc;
        }
    }
}

// ---- pass 2: cross-tile boundary scores from dumped rows ----
// grid: 8*15 blocks x 64 threads; block g: b = g/15, mt = g%15
__global__ void bnd_k(const unsigned short* __restrict__ ybnd,
                      float* __restrict__ pn, float* __restrict__ pc) {
    int b = blockIdx.x / 15, mt = blockIdx.x % 15;
    const unsigned short* T0 = ybnd + ((size_t)(b * 16 + mt) * 4) * 1024;
    const unsigned short* T1 = T0 + 4 * 1024;
    int l = threadIdx.x;
    float n255 = 0.f, c254 = 0.f, c255 = 0.f;
    #pragma unroll
    for (int k = 0; k < 16; ++k) {
        int c = l * 16 + k;
        float s2 = bf2f(T0[2 * 1024 + c]);   // C row 254
        float s3 = bf2f(T0[3 * 1024 + c]);   // C row 255
        float u0 = bf2f(T1[0 * 1024 + c]);   // C row 256
        float u1 = bf2f(T1[1 * 1024 + c]);   // C row 257
        float d254 = s3 - s2, d255 = u0 - s3, d256 = u1 - u0;
        n255 += d255 * d255; c254 += d254 * d255; c255 += d255 * d256;
    }
    #pragma unroll
    for (int off = 32; off > 0; off >>= 1) {
        n255 += __shfl_down(n255, off);
        c254 += __shfl_down(c254, off);
        c255 += __shfl_down(c255, off);
    }
    if (l == 0) {
        int i255 = mt * 256 + 255;
        float4 vn = {n255, 0.f, 0.f, 0.f};
        float4 va = {c254, 0.f, 0.f, 0.f};
        float4 vb = {c255, 0.f, 0.f, 0.f};
        *(float4*)(pn + ((size_t)b * SS + i255) * 4) = vn;
        *(float4*)(pc + ((size_t)b * SS + i255 - 1) * 4) = va;
        *(float4*)(pc + ((size_t)b * SS + i255) * 4) = vb;
    }
}

// ---- pass 3: combine partials -> scores -> adj ----
__global__ void score_k(const float* __restrict__ pn, const float* __restrict__ pc,
                        const float* __restrict__ gate, float* __restrict__ out) {
    int tid = blockIdx.x * 256 + threadIdx.x;
    if (tid >= NB * NI) return;
    int b = tid / NI;
    int i = tid - b * NI;
    size_t base = ((size_t)b * SS + i) * 4;
    float n0 = 0.f, n1 = 0.f, c0 = 0.f;
    #pragma unroll
    for (int j = 0; j < 4; ++j) {
        n0 += pn[base + j];
        n1 += pn[base + 4 + j];
        c0 += pc[base + j];
    }
    float d1a = sqrtf(fmaxf(n0, 0.f));
    float d1b = sqrtf(fmaxf(n1, 0.f));
    float d2  = sqrtf(fmaxf(n0 + 2.f * c0 + n1, 0.f));
    float s = fmaxf(1.f - (d1a + d1b - d2) / fmaxf(d2, 1e-6f), 0.f);
    float g = gate[0] * 0.5f;
    out[(size_t)b * SS + i + 1] = g * (s * (1.f / (float)NI) - 0.5f) * 0.1f;
    if (i == 0) {
        float e = g * (-0.5f) * 0.1f;
        out[(size_t)b * SS] = e;
        out[(size_t)b * SS + SS - 1] = e;
    }
}

extern "C" void kernel_launch(void* const* d_in, const int* in_sizes, int n_in,
                              void* d_out, int out_size, void* d_ws, size_t ws_size,
                              hipStream_t stream) {
    const float* x    = (const float*)d_in[0];
    const float* W    = (const float*)d_in[1];
    // d_in[2] (bias) cancels in all distances -> unused
    const float* gate = (const float*)d_in[3];
    float* out = (float*)d_out;
    char* ws = (char*)d_ws;

    unsigned short* Wb   = (unsigned short*)(ws + WB_OFF);
    unsigned short* xb   = (unsigned short*)(ws + XB_OFF);
    unsigned short* ybnd = (unsigned short*)(ws + YB_OFF);
    float* pn = (float*)(ws + PN_OFF);
    float* pc = (float*)(ws + PC_OFF);

    conv_w<<<1024, 256, 0, stream>>>(W, Wb);
    conv_xb<<<16384, 256, 0, stream>>>(x, xb);
    gemm_nc<<<512, 512, 0, stream>>>(xb, Wb, pn, pc, ybnd);
    bnd_k<<<NB * 15, 64, 0, stream>>>(ybnd, pn, pc);
    score_k<<<(NB * NI + 255) / 256, 256, 0, stream>>>(pn, pc, gate, out);
}

// Round 5
// 109.636 us; speedup vs baseline: 1.6362x; 1.0038x over previous
//
#include <hip/hip_runtime.h>
#include <hip/hip_bf16.h>

#define NB 8
#define SS 4096
#define DD 1024
#define NI 4094
#define NT 32       // K-tiles (BK=32)
#define BK 32

typedef __attribute__((ext_vector_type(8))) short short8;
typedef __attribute__((ext_vector_type(4))) float f32x4;

// ---- ws layout (bytes) ----
#define WB_OFF 0                           // Wb bf16 [1024][1024] swizzled   (2 MB)
#define XB_OFF (2*1024*1024)               // xb bf16 [8][4096][1024] swizzled(64 MB)
#define YB_OFF (XB_OFF + NB*SS*DD*2)       // ybnd bf16 [8][16][4][1024]      (1 MB)
#define PN_OFF (YB_OFF + NB*16*4*1024*2)   // pn f32 [8][4096][4]
#define PC_OFF (PN_OFF + NB*SS*4*4)        // pc f32 [8][4096][4]

// Swizzle: within each 32-k group (4 x 16B slots), logical slot s of row r is
// stored at physical slot s ^ ((r>>1)&3). Involution; baked into converters so
// gemm's global_load_lds sources stay LINEAR; ds_read applies the same XOR.

__device__ __forceinline__ unsigned short f2bf(float f) {
    union { float f; unsigned int u; } v; v.f = f;
    unsigned int r = v.u + 0x7FFFu + ((v.u >> 16) & 1u);   // RNE
    return (unsigned short)(r >> 16);
}
__device__ __forceinline__ float bf2f(unsigned short u) {
    union { unsigned int u; float f; } v; v.u = ((unsigned int)u) << 16;
    return v.f;
}
__device__ __forceinline__ void gload_lds16(const void* g, void* l) {
    __builtin_amdgcn_global_load_lds(
        (const __attribute__((address_space(1))) void*)g,
        (__attribute__((address_space(3))) void*)l, 16, 0, 0);
}

// ---- pass 0a: W -> bf16, slot-swizzled ----
__global__ void conv_w(const float* __restrict__ W, unsigned short* __restrict__ Wb) {
    int tid = blockIdx.x * 256 + threadIdx.x;   // 131072 threads, 8 elems each
    int row = tid >> 7;
    int sl  = tid & 127;
    int k0  = (sl >> 2) * 32;
    int s   = sl & 3;
    const float* p = W + (size_t)row * DD + k0 + s * 8;
    float4 a0 = *(const float4*)p;
    float4 a1 = *(const float4*)(p + 4);
    ushort4 o0, o1;
    o0.x = f2bf(a0.x); o0.y = f2bf(a0.y); o0.z = f2bf(a0.z); o0.w = f2bf(a0.w);
    o1.x = f2bf(a1.x); o1.y = f2bf(a1.y); o1.z = f2bf(a1.z); o1.w = f2bf(a1.w);
    int sw = s ^ ((row >> 1) & 3);
    unsigned short* q = Wb + (size_t)row * DD + k0 + sw * 8;
    *(ushort4*)q = o0;
    *(ushort4*)(q + 4) = o1;
}

// ---- pass 0b: x -> bf16, slot-swizzled ----
__global__ void conv_xb(const float* __restrict__ x, unsigned short* __restrict__ xb) {
    int tid = blockIdx.x * 256 + threadIdx.x;   // NB*SS*128 threads, 8 elems each
    int row = tid >> 7;                          // global row over b*S
    int sl  = tid & 127;
    int k0  = (sl >> 2) * 32;
    int s   = sl & 3;
    const float* p = x + (size_t)row * DD + k0 + s * 8;
    float4 a0 = *(const float4*)p;
    float4 a1 = *(const float4*)(p + 4);
    ushort4 o0, o1;
    o0.x = f2bf(a0.x); o0.y = f2bf(a0.y); o0.z = f2bf(a0.z); o0.w = f2bf(a0.w);
    o1.x = f2bf(a1.x); o1.y = f2bf(a1.y); o1.z = f2bf(a1.z); o1.w = f2bf(a1.w);
    int sw = s ^ ((row >> 1) & 3);
    unsigned short* q = xb + (size_t)row * DD + k0 + sw * 8;
    *(ushort4*)q = o0;
    *(ushort4*)(q + 4) = o1;
}

// ---- pass 1: GEMM C = xb @ Wb^T, 256x256 tile, BK=32, 8 waves,
//      3-buffer LDS pipeline, stage-2-ahead, counted vmcnt, raw s_barrier,
//      conflict-free swizzled LDS. Fused adjacent-row-diff epilogue.
__launch_bounds__(512, 2)
__global__ void gemm_nc(const unsigned short* __restrict__ xb,
                        const unsigned short* __restrict__ Wb,
                        float* __restrict__ pn, float* __restrict__ pc,
                        unsigned short* __restrict__ ybnd) {
    __shared__ __align__(16) char smem[98304];   // 3 x (A 16K + B 16K)

    const int bid = blockIdx.x;
    const int vb  = (bid & 7) * 64 + (bid >> 3);   // XCD-chunk swizzle (512 = 8*64)
    const int mg  = vb >> 2, bn = vb & 3;          // m-group, n-tile
    const int b   = mg >> 4, mt = mg & 15;
    const int m0  = mt * 256;

    const int t = threadIdx.x;
    const int lane = t & 63, w = t >> 6;           // 8 waves
    const int wr = w >> 2, wc = w & 3;             // 2 x 4 wave grid
    const int lrow = lane & 15, lgrp = lane >> 4;
    const int swo = (((lrow >> 1) & 3) ^ lgrp) << 4;  // per-thread constant XOR slot

    const unsigned short* Abase = xb + ((size_t)b * SS + m0) * DD;
    const unsigned short* Bbase = Wb + (size_t)bn * 256 * DD;

    const int sr0 = w * 16 + (lane >> 2);
    const int sc0 = (lane & 3) * 8;

    f32x4 acc[8][4] = {};

    char* p0 = smem;
    char* p1 = smem + 32768;
    char* p2 = smem + 65536;

    auto stage = [&](int kt, char* buf) {
        const int k0 = kt * BK;
        gload_lds16(Abase + (size_t)sr0 * DD + k0 + sc0,         buf + w * 1024);
        gload_lds16(Abase + (size_t)(sr0 + 128) * DD + k0 + sc0, buf + 8192 + w * 1024);
        gload_lds16(Bbase + (size_t)sr0 * DD + k0 + sc0,         buf + 16384 + w * 1024);
        gload_lds16(Bbase + (size_t)(sr0 + 128) * DD + k0 + sc0, buf + 16384 + 8192 + w * 1024);
    };

    stage(0, p0);
    stage(1, p1);
    asm volatile("s_waitcnt vmcnt(4)" ::: "memory");
    __builtin_amdgcn_s_barrier();
    asm volatile("" ::: "memory");

    for (int kt = 0; kt < NT; ++kt) {
        const char* A = p0;
        const char* B = p0 + 16384;
        short8 af[8], bfv[4];
        #pragma unroll
        for (int m = 0; m < 8; ++m)
            af[m] = *(const short8*)(A + (wr * 128 + m * 16 + lrow) * 64 + swo);
        #pragma unroll
        for (int n = 0; n < 4; ++n)
            bfv[n] = *(const short8*)(B + (wc * 64 + n * 16 + lrow) * 64 + swo);

        if (kt < NT - 2) {
            stage(kt + 2, p2);
            asm volatile("s_waitcnt vmcnt(4)" ::: "memory");  // stage(kt+1) landed (own)
        } else {
            asm volatile("s_waitcnt vmcnt(0)" ::: "memory");  // tail drain
        }
        asm volatile("s_waitcnt lgkmcnt(0)" ::: "memory");     // frag reads done pre-barrier
        __builtin_amdgcn_s_barrier();                          // all waves landed
        asm volatile("" ::: "memory");
        __builtin_amdgcn_sched_barrier(0);

        __builtin_amdgcn_s_setprio(1);
        #pragma unroll
        for (int m = 0; m < 8; ++m)
            #pragma unroll
            for (int n = 0; n < 4; ++n)
                acc[m][n] = __builtin_amdgcn_mfma_f32_16x16x32_bf16(
                    af[m], bfv[n], acc[m][n], 0, 0, 0);
        __builtin_amdgcn_s_setprio(0);

        char* tmp = p0; p0 = p1; p1 = p2; p2 = tmp;            // rotate buffers
    }

    // ---------------- epilogue ----------------
    __syncthreads();
    unsigned short* Y = (unsigned short*)smem;
    const int YP = 264;   // padded cols

    // chunk A: C rows 0..129
    if (wr == 0) {
        #pragma unroll
        for (int m = 0; m < 8; ++m) {
            int rbase = m * 16 + lgrp * 4;
            #pragma unroll
            for (int n = 0; n < 4; ++n) {
                int col = wc * 64 + n * 16 + lrow;
                #pragma unroll
                for (int j = 0; j < 4; ++j)
                    Y[(rbase + j) * YP + col] = f2bf(acc[m][n][j]);
            }
        }
    } else if (lgrp == 0) {   // rows 128,129 from wr=1, m=0, j=0,1
        #pragma unroll
        for (int n = 0; n < 4; ++n) {
            int col = wc * 64 + n * 16 + lrow;
            #pragma unroll
            for (int j = 0; j < 2; ++j)
                Y[(128 + j) * YP + col] = f2bf(acc[0][n][j]);
        }
    }
    __syncthreads();

    // dump C rows 0,1 (slots 0,1)
    if (t < 256) {
        int rr = t >> 7, cc = (t & 127) * 2;
        ushort2 v;
        v.x = Y[rr * YP + cc]; v.y = Y[rr * YP + cc + 1];
        *(ushort2*)(ybnd + ((size_t)((b * 16 + mt) * 4 + rr)) * 1024 + bn * 256 + cc) = v;
    }
    // reduce rows 0..127
    {
        int r = t >> 2, q = t & 3;
        const unsigned short* y0 = Y + r * YP + q * 64;
        float sn = 0.f, sc = 0.f;
        #pragma unroll
        for (int c8 = 0; c8 < 8; ++c8) {
            short8 v0 = *(const short8*)(y0 + c8 * 8);
            short8 v1 = *(const short8*)(y0 + YP + c8 * 8);
            short8 v2 = *(const short8*)(y0 + 2 * YP + c8 * 8);
            #pragma unroll
            for (int j = 0; j < 8; ++j) {
                float f0 = bf2f((unsigned short)v0[j]);
                float f1 = bf2f((unsigned short)v1[j]);
                float f2 = bf2f((unsigned short)v2[j]);
                float d0 = f1 - f0, d1 = f2 - f1;
                sn += d0 * d0; sc += d0 * d1;
            }
        }
        sn += __shfl_xor(sn, 1); sn += __shfl_xor(sn, 2);
        sc += __shfl_xor(sc, 1); sc += __shfl_xor(sc, 2);
        if (q == 0) {
            size_t o = ((size_t)b * SS + m0 + r) * 4 + bn;
            pn[o] = sn; pc[o] = sc;
        }
    }
    __syncthreads();

    // chunk B: C rows 128..255 -> LDS rows 0..127
    if (wr == 1) {
        #pragma unroll
        for (int m = 0; m < 8; ++m) {
            int rbase = m * 16 + lgrp * 4;
            #pragma unroll
            for (int n = 0; n < 4; ++n) {
                int col = wc * 64 + n * 16 + lrow;
                #pragma unroll
                for (int j = 0; j < 4; ++j)
                    Y[(rbase + j) * YP + col] = f2bf(acc[m][n][j]);
            }
        }
    }
    __syncthreads();

    // dump C rows 254,255 (LDS rows 126,127 -> slots 2,3)
    if (t < 256) {
        int rr = t >> 7, cc = (t & 127) * 2;
        ushort2 v;
        v.x = Y[(126 + rr) * YP + cc]; v.y = Y[(126 + rr) * YP + cc + 1];
        *(ushort2*)(ybnd + ((size_t)((b * 16 + mt) * 4 + 2 + rr)) * 1024 + bn * 256 + cc) = v;
    }
    // reduce rows 128..254
    {
        int r2 = t >> 2, q = t & 3;
        float sn = 0.f, sc = 0.f;
        if (r2 <= 126) {
            const unsigned short* y0 = Y + r2 * YP + q * 64;
            int rc = (r2 < 126) ? 2 : 1;
            #pragma unroll
            for (int c8 = 0; c8 < 8; ++c8) {
                short8 v0 = *(const short8*)(y0 + c8 * 8);
                short8 v1 = *(const short8*)(y0 + YP + c8 * 8);
                short8 v2 = *(const short8*)(y0 + rc * YP + c8 * 8);
                #pragma unroll
                for (int j = 0; j < 8; ++j) {
                    float f0 = bf2f((unsigned short)v0[j]);
                    float f1 = bf2f((unsigned short)v1[j]);
                    float f2 = bf2f((unsigned short)v2[j]);
                    float d0 = f1 - f0, d1 = f2 - f1;
                    sn += d0 * d0; sc += d0 * d1;
                }
            }
        }
        sn += __shfl_xor(sn, 1); sn += __shfl_xor(sn, 2);
        sc += __shfl_xor(sc, 1); sc += __shfl_xor(sc, 2);
        if (q == 0 && r2 <= 126) {
            size_t o = ((size_t)b * SS + m0 + 128 + r2) * 4 + bn;
            pn[o] = sn;
            if (r2 <= 125) pc[o] = sc;
        }
    }
}

// ---- pass 2: cross-tile boundary scores from dumped rows ----
__global__ void bnd_k(const unsigned short* __restrict__ ybnd,
                      float* __restrict__ pn, float* __restrict__ pc) {
    int b = blockIdx.x / 15, mt = blockIdx.x % 15;
    const unsigned short* T0 = ybnd + ((size_t)(b * 16 + mt) * 4) * 1024;
    const unsigned short* T1 = T0 + 4 * 1024;
    int l = threadIdx.x;
    float n255 = 0.f, c254 = 0.f, c255 = 0.f;
    #pragma unroll
    for (int k = 0; k < 16; ++k) {
        int c = l * 16 + k;
        float s2 = bf2f(T0[2 * 1024 + c]);   // C row 254
        float s3 = bf2f(T0[3 * 1024 + c]);   // C row 255
        float u0 = bf2f(T1[0 * 1024 + c]);   // C row 256
        float u1 = bf2f(T1[1 * 1024 + c]);   // C row 257
        float d254 = s3 - s2, d255 = u0 - s3, d256 = u1 - u0;
        n255 += d255 * d255; c254 += d254 * d255; c255 += d255 * d256;
    }
    #pragma unroll
    for (int off = 32; off > 0; off >>= 1) {
        n255 += __shfl_down(n255, off);
        c254 += __shfl_down(c254, off);
        c255 += __shfl_down(c255, off);
    }
    if (l == 0) {
        int i255 = mt * 256 + 255;
        float4 vn = {n255, 0.f, 0.f, 0.f};
        float4 va = {c254, 0.f, 0.f, 0.f};
        float4 vb = {c255, 0.f, 0.f, 0.f};
        *(float4*)(pn + ((size_t)b * SS + i255) * 4) = vn;
        *(float4*)(pc + ((size_t)b * SS + i255 - 1) * 4) = va;
        *(float4*)(pc + ((size_t)b * SS + i255) * 4) = vb;
    }
}

// ---- pass 3: combine partials -> scores -> adj ----
__global__ void score_k(const float* __restrict__ pn, const float* __restrict__ pc,
                        const float* __restrict__ gate, float* __restrict__ out) {
    int tid = blockIdx.x * 256 + threadIdx.x;
    if (tid >= NB * NI) return;
    int b = tid / NI;
    int i = tid - b * NI;
    size_t base = ((size_t)b * SS + i) * 4;
    float n0 = 0.f, n1 = 0.f, c0 = 0.f;
    #pragma unroll
    for (int j = 0; j < 4; ++j) {
        n0 += pn[base + j];
        n1 += pn[base + 4 + j];
        c0 += pc[base + j];
    }
    float d1a = sqrtf(fmaxf(n0, 0.f));
    float d1b = sqrtf(fmaxf(n1, 0.f));
    float d2  = sqrtf(fmaxf(n0 + 2.f * c0 + n1, 0.f));
    float s = fmaxf(1.f - (d1a + d1b - d2) / fmaxf(d2, 1e-6f), 0.f);
    float g = gate[0] * 0.5f;
    out[(size_t)b * SS + i + 1] = g * (s * (1.f / (float)NI) - 0.5f) * 0.1f;
    if (i == 0) {
        float e = g * (-0.5f) * 0.1f;
        out[(size_t)b * SS] = e;
        out[(size_t)b * SS + SS - 1] = e;
    }
}

extern "C" void kernel_launch(void* const* d_in, const int* in_sizes, int n_in,
                              void* d_out, int out_size, void* d_ws, size_t ws_size,
                              hipStream_t stream) {
    const float* x    = (const float*)d_in[0];
    const float* W    = (const float*)d_in[1];
    // d_in[2] (bias) cancels in all distances -> unused
    const float* gate = (const float*)d_in[3];
    float* out = (float*)d_out;
    char* ws = (char*)d_ws;

    unsigned short* Wb   = (unsigned short*)(ws + WB_OFF);
    unsigned short* xb   = (unsigned short*)(ws + XB_OFF);
    unsigned short* ybnd = (unsigned short*)(ws + YB_OFF);
    float* pn = (float*)(ws + PN_OFF);
    float* pc = (float*)(ws + PC_OFF);

    conv_w<<<512, 256, 0, stream>>>(W, Wb);
    conv_xb<<<NB * SS * 128 / 256, 256, 0, stream>>>(x, xb);
    gemm_nc<<<512, 512, 0, stream>>>(xb, Wb, pn, pc, ybnd);
    bnd_k<<<NB * 15, 64, 0, stream>>>(ybnd, pn, pc);
    score_k<<<(NB * NI + 255) / 256, 256, 0, stream>>>(pn, pc, gate, out);
}